// Round 4
// baseline (117.755 us; speedup 1.0000x reference)
//
#include <hip/hip_runtime.h>
#include <hip/hip_bf16.h>

// Shapes (fixed by the reference)
#define NB 8
#define NS 1024
#define ND 512
#define NH 8
#define NDK 64

typedef __attribute__((ext_vector_type(8))) short bf16x8;
typedef __attribute__((ext_vector_type(4))) short s16x4;
typedef __attribute__((ext_vector_type(4))) float f32x4;
typedef __attribute__((ext_vector_type(16))) float f32x16;

// scores are computed in exp2 domain: Q is pre-scaled by 0.125 * log2(e)
#define QSCALE 0.18033688011112042f
#define NEGBIG -3.0e38f

#define CVTPK(dst, a, b) \
    asm("v_cvt_pk_bf16_f32 %0, %1, %2" : "=v"(dst) : "v"(a), "v"(b))
#define PLSWAP(a, b) \
    asm("v_permlane32_swap_b32 %0, %1" : "+v"(a), "+v"(b))

__device__ __forceinline__ unsigned short bfround(float f) {
    union { float f; unsigned u; } v; v.f = f;
    unsigned u = v.u;
    u += 0x7fffu + ((u >> 16) & 1u);
    return (unsigned short)(u >> 16);
}

// ---------------------------------------------------------------------------
// Kernel 1: transpose + convert the four 512x512 fp32 weights ([in][out]) into
// bf16 Wt[out][in] so the GEMM B-operand (k-contiguous per lane) reads linearly.
// ---------------------------------------------------------------------------
__global__ __launch_bounds__(256) void wt_kernel(const float* __restrict__ W0,
                                                 const float* __restrict__ W1,
                                                 const float* __restrict__ W2,
                                                 const float* __restrict__ W3,
                                                 unsigned short* __restrict__ wt) {
    __shared__ float sh[64][65];
    const int z = blockIdx.z;
    const float* W = z == 0 ? W0 : z == 1 ? W1 : z == 2 ? W2 : W3;
    unsigned short* out = wt + (size_t)z * ND * ND;
    const int o0 = blockIdx.x * 64, i0 = blockIdx.y * 64;
    const int tx = threadIdx.x & 63;
    const int ty = threadIdx.x >> 6;  // 0..3
    #pragma unroll
    for (int rr = 0; rr < 16; ++rr) {
        const int row = ty * 16 + rr;  // local i
        sh[row][tx] = W[(size_t)(i0 + row) * ND + o0 + tx];
    }
    __syncthreads();
    #pragma unroll
    for (int rr = 0; rr < 16; ++rr) {
        const int row = ty * 16 + rr;  // local o
        out[(size_t)(o0 + row) * ND + i0 + tx] = bfround(sh[tx][row]);
    }
}

// ---------------------------------------------------------------------------
// Kernel 2/5: GEMM  out = A(8192x512) @ W(512x512) + bias  (unchanged, passing)
// ---------------------------------------------------------------------------
template <bool A_F32, bool OUT_F32>
__global__ __launch_bounds__(256) void gemm_kernel(
    const void* __restrict__ A0, const void* __restrict__ A1, const void* __restrict__ A2,
    const unsigned short* __restrict__ wt_base, int wt_stride,
    const float* __restrict__ b0, const float* __restrict__ b1, const float* __restrict__ b2,
    void* __restrict__ out_base, size_t out_stride_bytes) {
    __shared__ unsigned short As[128][40];
    __shared__ unsigned short Bs[128][40];
    const int t = threadIdx.x;
    const int lane = t & 63, w = t >> 6;
    const int wr = w >> 1, wc = w & 1;
    const int lr = lane & 15, lg = lane >> 4;
    const int bid = blockIdx.x;
    const int u = (bid & 7) * (gridDim.x >> 3) + (bid >> 3);
    const int xt = u & 3, yt = (u >> 2) & 63, z = u >> 8;
    const void* Ap = z == 0 ? A0 : z == 1 ? A1 : A2;
    const float* bias = z == 0 ? b0 : z == 1 ? b1 : b2;
    const unsigned short* Wt = wt_base + (size_t)z * wt_stride;
    void* outp = (void*)((char*)out_base + (size_t)z * out_stride_bytes);
    const int m0 = yt * 128, n0 = xt * 128;

    f32x4 acc[4][4];
    #pragma unroll
    for (int i = 0; i < 4; ++i)
        #pragma unroll
        for (int j = 0; j < 4; ++j) acc[i][j] = (f32x4){0.f, 0.f, 0.f, 0.f};

    for (int kt = 0; kt < 16; ++kt) {
        const int k0 = kt * 32;
        __syncthreads();
        if (A_F32) {
            const float* A = (const float*)Ap;
            const int mrow = t >> 3, k4 = (t & 7) * 4;
            #pragma unroll
            for (int r = 0; r < 4; ++r) {
                const int m = mrow + 32 * r;
                float4 v = *(const float4*)(A + (size_t)(m0 + m) * ND + k0 + k4);
                unsigned p0, p1;
                CVTPK(p0, v.x, v.y);
                CVTPK(p1, v.z, v.w);
                uint2 pv; pv.x = p0; pv.y = p1;
                *(uint2*)(&As[m][k4]) = pv;
            }
        } else {
            const unsigned short* A = (const unsigned short*)Ap;
            #pragma unroll
            for (int r = 0; r < 2; ++r) {
                const int idx = t + 256 * r;
                const int m = idx >> 2, k8 = (idx & 3) * 8;
                *(bf16x8*)(&As[m][k8]) =
                    *(const bf16x8*)(A + (size_t)(m0 + m) * ND + k0 + k8);
            }
        }
        #pragma unroll
        for (int r = 0; r < 2; ++r) {
            const int idx = t + 256 * r;
            const int n = idx >> 2, k8 = (idx & 3) * 8;
            *(bf16x8*)(&Bs[n][k8]) =
                *(const bf16x8*)(Wt + (size_t)(n0 + n) * ND + k0 + k8);
        }
        __syncthreads();
        bf16x8 af[4], bfv[4];
        #pragma unroll
        for (int mi = 0; mi < 4; ++mi)
            af[mi] = *(const bf16x8*)(&As[wr * 64 + mi * 16 + lr][lg * 8]);
        #pragma unroll
        for (int nj = 0; nj < 4; ++nj)
            bfv[nj] = *(const bf16x8*)(&Bs[wc * 64 + nj * 16 + lr][lg * 8]);
        #pragma unroll
        for (int mi = 0; mi < 4; ++mi)
            #pragma unroll
            for (int nj = 0; nj < 4; ++nj)
                acc[mi][nj] = __builtin_amdgcn_mfma_f32_16x16x32_bf16(
                    af[mi], bfv[nj], acc[mi][nj], 0, 0, 0);
    }

    const float osc = (!OUT_F32 && z == 0) ? QSCALE : 1.0f;
    #pragma unroll
    for (int mi = 0; mi < 4; ++mi) {
        #pragma unroll
        for (int nj = 0; nj < 4; ++nj) {
            const int n = n0 + wc * 64 + nj * 16 + lr;
            const float bv = bias[n];
            #pragma unroll
            for (int r = 0; r < 4; ++r) {
                const int m = m0 + wr * 64 + mi * 16 + lg * 4 + r;
                const float val = (acc[mi][nj][r] + bv) * osc;
                if (OUT_F32) {
                    ((float*)outp)[(size_t)m * ND + n] = val;
                } else {
                    const int bb = m >> 10, s = m & 1023;    // m = b*S + s
                    const int hh = n >> 6, dk = n & 63;      // n = h*64 + dk
                    ((unsigned short*)outp)[(((size_t)(bb * NH + hh) * NS + s) << 6) + dk] =
                        bfround(val);
                }
            }
        }
    }
}

// ---------------------------------------------------------------------------
// Kernel 3: per-(b,h) transpose V (S,DK) -> Vt (DK,S). (unchanged, passing)
// ---------------------------------------------------------------------------
__global__ __launch_bounds__(256) void vt_kernel(const unsigned short* __restrict__ Vb,
                                                 unsigned short* __restrict__ Vt) {
    __shared__ unsigned short Ts[64][72];
    const int t = threadIdx.x;
    const int bh = blockIdx.y;
    const int s0 = blockIdx.x * 64;
    const unsigned short* Vh = Vb + (size_t)bh * NS * NDK;
    unsigned short* Vth = Vt + (size_t)bh * NDK * NS;
    #pragma unroll
    for (int r = 0; r < 2; ++r) {
        const int idx = t + 256 * r;
        const int sl = idx >> 3, d8 = (idx & 7) * 8;
        *(bf16x8*)(&Ts[sl][d8]) = *(const bf16x8*)(Vh + (size_t)(s0 + sl) * NDK + d8);
    }
    __syncthreads();
    #pragma unroll
    for (int r = 0; r < 2; ++r) {
        const int idx = t + 256 * r;
        const int dl = idx >> 3, s8 = (idx & 7) * 8;
        unsigned short tmp[8];
        #pragma unroll
        for (int e = 0; e < 8; ++e) tmp[e] = Ts[s8 + e][dl];
        *(bf16x8*)(Vth + (size_t)dl * NS + s0 + s8) = *(bf16x8*)tmp;
    }
}

// ---------------------------------------------------------------------------
// Kernel 4: flash attention, swapped-operand 32x32 MFMA, in-register softmax,
// register-pipelined loads. K double-buffered across iterations (prefetch
// distance 1); V single-buffered with intra-iteration slack (issued at iter
// top, consumed after softmax). sched_barrier(0) after each load batch
// prevents the compiler from sinking loads to their use (the R3 failure:
// VGPR minimized to 60 -> 16 serialized L2 round-trips per iter).
// ---------------------------------------------------------------------------
struct AttnState {
    f32x16 acc0, acc1;
    float m_st, l_st;
};

__device__ __forceinline__ void attn_step(const bf16x8 (&kf)[8], const bf16x8 (&vv)[8],
                                          const bf16x8 (&qf)[4], int mval,
                                          float* __restrict__ brow, int lane, int hi,
                                          AttnState& st) {
    // mask bias -> per-wave LDS row (ds_write latency hides under QK MFMAs)
    brow[lane] = mval ? 0.f : NEGBIG;

    f32x16 sc0 = {}, sc1 = {};
    __builtin_amdgcn_s_setprio(1);
    sc0 = __builtin_amdgcn_mfma_f32_32x32x16_bf16(kf[0], qf[0], sc0, 0, 0, 0);
    sc1 = __builtin_amdgcn_mfma_f32_32x32x16_bf16(kf[4], qf[0], sc1, 0, 0, 0);
    sc0 = __builtin_amdgcn_mfma_f32_32x32x16_bf16(kf[1], qf[1], sc0, 0, 0, 0);
    sc1 = __builtin_amdgcn_mfma_f32_32x32x16_bf16(kf[5], qf[1], sc1, 0, 0, 0);
    sc0 = __builtin_amdgcn_mfma_f32_32x32x16_bf16(kf[2], qf[2], sc0, 0, 0, 0);
    sc1 = __builtin_amdgcn_mfma_f32_32x32x16_bf16(kf[6], qf[2], sc1, 0, 0, 0);
    sc0 = __builtin_amdgcn_mfma_f32_32x32x16_bf16(kf[3], qf[3], sc0, 0, 0, 0);
    sc1 = __builtin_amdgcn_mfma_f32_32x32x16_bf16(kf[7], qf[3], sc1, 0, 0, 0);
    __builtin_amdgcn_s_setprio(0);

    // mask bias: rows of reg-group mm are 8*mm + 4*hi + {0..3}
    {
        const float* bl = brow + 4 * hi;
        #pragma unroll
        for (int mm = 0; mm < 4; ++mm) {
            const f32x4 bv0 = *(const f32x4*)(bl + 8 * mm);
            const f32x4 bv1 = *(const f32x4*)(bl + 32 + 8 * mm);
            #pragma unroll
            for (int c = 0; c < 4; ++c) {
                sc0[4 * mm + c] += bv0[c];
                sc1[4 * mm + c] += bv1[c];
            }
        }
    }

    // row max (lane holds 32 of 64 kv entries; partner lane has the rest)
    float tv[16];
    #pragma unroll
    for (int r = 0; r < 16; ++r) tv[r] = fmaxf(sc0[r], sc1[r]);
    #pragma unroll
    for (int s = 8; s > 0; s >>= 1)
        #pragma unroll
        for (int r = 0; r < 16; ++r)
            if (r < s) tv[r] = fmaxf(tv[r], tv[r + s]);
    const float mx = fmaxf(tv[0], __shfl_xor(tv[0], 32));
    const float mn = fmaxf(st.m_st, mx);

    // exp2 + row sum
    #pragma unroll
    for (int r = 0; r < 16; ++r) {
        sc0[r] = __builtin_amdgcn_exp2f(sc0[r] - mn);
        sc1[r] = __builtin_amdgcn_exp2f(sc1[r] - mn);
    }
    #pragma unroll
    for (int r = 0; r < 16; ++r) tv[r] = sc0[r] + sc1[r];
    #pragma unroll
    for (int s = 8; s > 0; s >>= 1)
        #pragma unroll
        for (int r = 0; r < 16; ++r)
            if (r < s) tv[r] += tv[r + s];
    const float rs = tv[0] + __shfl_xor(tv[0], 32);

    const bool ch = mn > st.m_st;
    if (__any(ch)) {
        const float f = __builtin_amdgcn_exp2f(st.m_st - mn);
        st.l_st = st.l_st * f + rs;
        st.m_st = mn;
        #pragma unroll
        for (int r = 0; r < 16; ++r) { st.acc0[r] *= f; st.acc1[r] *= f; }
    } else {
        st.l_st += rs;
    }

    // P -> bf16 PV B-frags in-register (T12): words w[m] cover rows
    // 8m+4hi+{0..3}; swap(w[m], w[m+1]) yields frag regs (lo->{0,1}, hi->{2,3})
    union U8 { unsigned u[4]; bf16x8 v; };
    bf16x8 pA0, pA1, pB0, pB1;
    {
        unsigned w00, w01, w10, w11, w20, w21, w30, w31;
        CVTPK(w00, sc0[0], sc0[1]);  CVTPK(w01, sc0[2], sc0[3]);
        CVTPK(w10, sc0[4], sc0[5]);  CVTPK(w11, sc0[6], sc0[7]);
        CVTPK(w20, sc0[8], sc0[9]);  CVTPK(w21, sc0[10], sc0[11]);
        CVTPK(w30, sc0[12], sc0[13]); CVTPK(w31, sc0[14], sc0[15]);
        PLSWAP(w00, w10); PLSWAP(w01, w11);
        PLSWAP(w20, w30); PLSWAP(w21, w31);
        U8 f0; f0.u[0] = w00; f0.u[1] = w01; f0.u[2] = w10; f0.u[3] = w11;
        U8 f1; f1.u[0] = w20; f1.u[1] = w21; f1.u[2] = w30; f1.u[3] = w31;
        pA0 = f0.v; pA1 = f1.v;
    }
    {
        unsigned w00, w01, w10, w11, w20, w21, w30, w31;
        CVTPK(w00, sc1[0], sc1[1]);  CVTPK(w01, sc1[2], sc1[3]);
        CVTPK(w10, sc1[4], sc1[5]);  CVTPK(w11, sc1[6], sc1[7]);
        CVTPK(w20, sc1[8], sc1[9]);  CVTPK(w21, sc1[10], sc1[11]);
        CVTPK(w30, sc1[12], sc1[13]); CVTPK(w31, sc1[14], sc1[15]);
        PLSWAP(w00, w10); PLSWAP(w01, w11);
        PLSWAP(w20, w30); PLSWAP(w21, w31);
        U8 f0; f0.u[0] = w00; f0.u[1] = w01; f0.u[2] = w10; f0.u[3] = w11;
        U8 f1; f1.u[0] = w20; f1.u[1] = w21; f1.u[2] = w30; f1.u[3] = w31;
        pB0 = f0.v; pB1 = f1.v;
    }

    // O^T += V^T P
    __builtin_amdgcn_s_setprio(1);
    st.acc0 = __builtin_amdgcn_mfma_f32_32x32x16_bf16(vv[0], pA0, st.acc0, 0, 0, 0);
    st.acc1 = __builtin_amdgcn_mfma_f32_32x32x16_bf16(vv[4], pA0, st.acc1, 0, 0, 0);
    st.acc0 = __builtin_amdgcn_mfma_f32_32x32x16_bf16(vv[1], pA1, st.acc0, 0, 0, 0);
    st.acc1 = __builtin_amdgcn_mfma_f32_32x32x16_bf16(vv[5], pA1, st.acc1, 0, 0, 0);
    st.acc0 = __builtin_amdgcn_mfma_f32_32x32x16_bf16(vv[2], pB0, st.acc0, 0, 0, 0);
    st.acc1 = __builtin_amdgcn_mfma_f32_32x32x16_bf16(vv[6], pB0, st.acc1, 0, 0, 0);
    st.acc0 = __builtin_amdgcn_mfma_f32_32x32x16_bf16(vv[3], pB1, st.acc0, 0, 0, 0);
    st.acc1 = __builtin_amdgcn_mfma_f32_32x32x16_bf16(vv[7], pB1, st.acc1, 0, 0, 0);
    __builtin_amdgcn_s_setprio(0);
}

__global__ __launch_bounds__(256, 2) void attn_kernel(const unsigned short* __restrict__ Qb,
                                                      const unsigned short* __restrict__ Kb,
                                                      const unsigned short* __restrict__ Vt,
                                                      const int* __restrict__ mask,
                                                      unsigned short* __restrict__ Xb) {
    __shared__ float bias_lds[4][64];
    const int t = threadIdx.x;
    const int lane = t & 63, w = t >> 6;
    const int q32 = lane & 31, hi = lane >> 5;
    // XCD swizzle: 8 q-tiles of one head contiguous on one XCD
    const int bid = blockIdx.x;                  // 512 blocks
    const int u = (bid & 7) * 64 + (bid >> 3);
    const int bh = u >> 3, xq = u & 7;
    const int b = bh >> 3, h = bh & 7;
    const int q = xq * 128 + w * 32 + q32;
    const unsigned short* Qh = Qb + (size_t)bh * NS * NDK;
    const unsigned short* Kh = Kb + (size_t)bh * NS * NDK;
    const unsigned short* Vh = Vt + (size_t)bh * NDK * NS;
    const int* mk = mask + b * NS;
    float* brow = &bias_lds[w][0];

    // Q fragments (B-operand: col=q, k=dk): 4 chunks of K=16
    bf16x8 qf[4];
    {
        const unsigned short* Qp = Qh + (size_t)q * NDK + hi * 8;
        qf[0] = *(const bf16x8*)(Qp + 0);
        qf[1] = *(const bf16x8*)(Qp + 16);
        qf[2] = *(const bf16x8*)(Qp + 32);
        qf[3] = *(const bf16x8*)(Qp + 48);
    }

    AttnState st;
    st.acc0 = (f32x16){}; st.acc1 = (f32x16){};
    st.m_st = -1.0e30f; st.l_st = 0.f;

    bf16x8 kA[8], kB[8], vv[8];

#define LOADK(dst, itx) do {                                                   \
        const unsigned short* _p = Kh + (size_t)((itx) * 64 + q32) * NDK + hi * 8; \
        dst[0] = *(const bf16x8*)(_p + 0);                                     \
        dst[1] = *(const bf16x8*)(_p + 16);                                    \
        dst[2] = *(const bf16x8*)(_p + 32);                                    \
        dst[3] = *(const bf16x8*)(_p + 48);                                    \
        const unsigned short* _p1 = _p + 32 * NDK;                             \
        dst[4] = *(const bf16x8*)(_p1 + 0);                                    \
        dst[5] = *(const bf16x8*)(_p1 + 16);                                   \
        dst[6] = *(const bf16x8*)(_p1 + 32);                                   \
        dst[7] = *(const bf16x8*)(_p1 + 48);                                   \
    } while (0)

#define LOADV(dst, itx) do {                                                   \
        const unsigned short* _p = Vh + (size_t)q32 * NS + (itx) * 64 + hi * 8; \
        dst[0] = *(const bf16x8*)(_p + 0);                                     \
        dst[1] = *(const bf16x8*)(_p + 16);                                    \
        dst[2] = *(const bf16x8*)(_p + 32);                                    \
        dst[3] = *(const bf16x8*)(_p + 48);                                    \
        const unsigned short* _p1 = _p + 32 * NS;                              \
        dst[4] = *(const bf16x8*)(_p1 + 0);                                    \
        dst[5] = *(const bf16x8*)(_p1 + 16);                                   \
        dst[6] = *(const bf16x8*)(_p1 + 32);                                   \
        dst[7] = *(const bf16x8*)(_p1 + 48);                                   \
    } while (0)

    LOADK(kA, 0);
    #pragma unroll 1
    for (int ii = 0; ii < 8; ++ii) {
        const int itE = ii * 2, itO = itE + 1;
        // even phase: V(itE) + K(itO) in flight; compute on kA
        const int mE = mk[itE * 64 + lane];
        LOADV(vv, itE);
        LOADK(kB, itO);
        __builtin_amdgcn_sched_barrier(0);
        attn_step(kA, vv, qf, mE, brow, lane, hi, st);
        // odd phase: V(itO) + K(itE+2) in flight; compute on kB
        const int mO = mk[itO * 64 + lane];
        const int itN = itO + 1 > 15 ? 15 : itO + 1;
        LOADV(vv, itO);
        LOADK(kA, itN);
        __builtin_amdgcn_sched_barrier(0);
        attn_step(kB, vv, qf, mO, brow, lane, hi, st);
    }
#undef LOADK
#undef LOADV

    // epilogue: X[b][q][h*64+dk] = O^T / l ; dk = od*32 + 8*mm + 4*hi + c
    const float inv = st.l_st > 0.f ? 1.f / st.l_st : 0.f;
    unsigned short* Xp = Xb + (size_t)(b * NS + q) * ND + h * 64 + 4 * hi;
    #pragma unroll
    for (int mm = 0; mm < 4; ++mm) {
        unsigned w0, w1;
        CVTPK(w0, st.acc0[4 * mm] * inv, st.acc0[4 * mm + 1] * inv);
        CVTPK(w1, st.acc0[4 * mm + 2] * inv, st.acc0[4 * mm + 3] * inv);
        uint2 pv; pv.x = w0; pv.y = w1;
        *(uint2*)(Xp + 8 * mm) = pv;
        CVTPK(w0, st.acc1[4 * mm] * inv, st.acc1[4 * mm + 1] * inv);
        CVTPK(w1, st.acc1[4 * mm + 2] * inv, st.acc1[4 * mm + 3] * inv);
        pv.x = w0; pv.y = w1;
        *(uint2*)(Xp + 32 + 8 * mm) = pv;
    }
}

// ---------------------------------------------------------------------------
// Host launcher. Workspace (bf16 elements): wt(4*512*512), Qb, Kb, Vb, Vt, Xb.
// ---------------------------------------------------------------------------
extern "C" void kernel_launch(void* const* d_in, const int* in_sizes, int n_in,
                              void* d_out, int out_size, void* d_ws, size_t ws_size,
                              hipStream_t stream) {
    const float* query = (const float*)d_in[0];
    const float* key   = (const float*)d_in[1];
    const float* value = (const float*)d_in[2];
    const int*   mask  = (const int*)d_in[3];
    const float* Wq = (const float*)d_in[4];
    const float* bq = (const float*)d_in[5];
    const float* Wk = (const float*)d_in[6];
    const float* bk = (const float*)d_in[7];
    const float* Wv = (const float*)d_in[8];
    const float* bv = (const float*)d_in[9];
    const float* Wo = (const float*)d_in[10];
    const float* bo = (const float*)d_in[11];

    const size_t HEADSZ = (size_t)NB * NH * NS * NDK;  // 4194304
    unsigned short* wt = (unsigned short*)d_ws;
    unsigned short* Qb = wt + (size_t)4 * ND * ND;
    unsigned short* Kb = Qb + HEADSZ;
    unsigned short* Vb = Kb + HEADSZ;
    unsigned short* Vt = Vb + HEADSZ;
    unsigned short* Xb = Vt + HEADSZ;

    // 1. weights -> bf16, transposed
    wt_kernel<<<dim3(8, 8, 4), 256, 0, stream>>>(Wq, Wk, Wv, Wo, wt);

    // 2. QKV projections (one launch, z = q/k/v); Q pre-scaled by QSCALE
    gemm_kernel<true, false><<<768, 256, 0, stream>>>(
        query, key, value, wt, ND * ND, bq, bk, bv, (void*)Qb, HEADSZ * 2);

    // 3. V -> V^T per head
    vt_kernel<<<dim3(16, NB * NH), 256, 0, stream>>>(Vb, Vt);

    // 4. attention (512 blocks, 4 waves each, no barriers)
    attn_kernel<<<512, 256, 0, stream>>>(Qb, Kb, Vt, mask, Xb);

    // 5. output projection (fp32 out)
    gemm_kernel<false, true><<<256, 256, 0, stream>>>(
        Xb, Xb, Xb, wt + (size_t)3 * ND * ND, 0, bo, bo, bo, d_out, 0);
}

// Round 5
// 85.040 us; speedup vs baseline: 1.3847x; 1.3847x over previous
//
#include <hip/hip_runtime.h>
#include <hip/hip_bf16.h>

// Shapes (fixed by the reference)
#define NB 8
#define NS 1024
#define ND 512
#define NH 8
#define NDK 64

typedef __attribute__((ext_vector_type(8))) short bf16x8;
typedef __attribute__((ext_vector_type(4))) short s16x4;
typedef __attribute__((ext_vector_type(4))) float f32x4;
typedef __attribute__((ext_vector_type(16))) float f32x16;

// scores are computed in exp2 domain: Q is pre-scaled by 0.125 * log2(e)
#define QSCALE 0.18033688011112042f
#define NEGBIG -3.0e38f

#define CVTPK(dst, a, b) \
    asm("v_cvt_pk_bf16_f32 %0, %1, %2" : "=v"(dst) : "v"(a), "v"(b))
#define PLSWAP(a, b) \
    asm("v_permlane32_swap_b32 %0, %1" : "+v"(a), "+v"(b))

__device__ __forceinline__ unsigned short bfround(float f) {
    union { float f; unsigned u; } v; v.f = f;
    unsigned u = v.u;
    u += 0x7fffu + ((u >> 16) & 1u);
    return (unsigned short)(u >> 16);
}

// ---------------------------------------------------------------------------
// Fragment-major global layouts for attention operands (16B chunk = 8 shorts,
// chunk index = [tile][j][lane]; a wave's chunk-j load is 64 lanes x 16B fully
// coalesced at uniform offset j*1024B).
//   QF: q-tile 32 rows:  chunk (qt*4 + kk),      lane = hi*32 + (q&31),  e = dk&7
//   KF: kv-tile 64 rows: chunk (it*8 + h2*4+kk), lane = hi*32 + (kv&31), e = dk&7
//   VF: kv-tile 64 rows: chunk (it*8 + od*4+kk), lane = hi*32 + (dk&31), e = kv&7
// ---------------------------------------------------------------------------
__device__ __forceinline__ size_t qf_off(int s, int dk) {
    return ((size_t)(((s >> 5) * 4 + (dk >> 4)) * 64 + ((dk >> 3) & 1) * 32 + (s & 31)) << 3) + (dk & 7);
}
__device__ __forceinline__ size_t kf_off(int s, int dk) {
    return ((size_t)(((s >> 6) * 8 + ((s >> 5) & 1) * 4 + (dk >> 4)) * 64 + ((dk >> 3) & 1) * 32 + (s & 31)) << 3) + (dk & 7);
}
__device__ __forceinline__ size_t vf_off(int s, int dk) {
    return ((size_t)(((s >> 6) * 8 + (dk >> 5) * 4 + ((s >> 4) & 3)) * 64 + ((s >> 3) & 1) * 32 + (dk & 31)) << 3) + (s & 7);
}

// ---------------------------------------------------------------------------
// Kernel 1: transpose + convert the four 512x512 fp32 weights ([in][out]) into
// bf16 Wt[out][in] so the GEMM B-operand (k-contiguous per lane) reads linearly.
// ---------------------------------------------------------------------------
__global__ __launch_bounds__(256) void wt_kernel(const float* __restrict__ W0,
                                                 const float* __restrict__ W1,
                                                 const float* __restrict__ W2,
                                                 const float* __restrict__ W3,
                                                 unsigned short* __restrict__ wt) {
    __shared__ float sh[64][65];
    const int z = blockIdx.z;
    const float* W = z == 0 ? W0 : z == 1 ? W1 : z == 2 ? W2 : W3;
    unsigned short* out = wt + (size_t)z * ND * ND;
    const int o0 = blockIdx.x * 64, i0 = blockIdx.y * 64;
    const int tx = threadIdx.x & 63;
    const int ty = threadIdx.x >> 6;  // 0..3
    #pragma unroll
    for (int rr = 0; rr < 16; ++rr) {
        const int row = ty * 16 + rr;  // local i
        sh[row][tx] = W[(size_t)(i0 + row) * ND + o0 + tx];
    }
    __syncthreads();
    #pragma unroll
    for (int rr = 0; rr < 16; ++rr) {
        const int row = ty * 16 + rr;  // local o
        out[(size_t)(o0 + row) * ND + i0 + tx] = bfround(sh[tx][row]);
    }
}

// ---------------------------------------------------------------------------
// Kernel 2/5: GEMM  out = A(8192x512) @ W(512x512) + bias
// A_F32: fp32 input converted to bf16 during staging. OUT_F32: fp32 [M][N]
// output (final projection); else bf16 into the fragment-major QF/KF/VF
// layouts (z = 0/1/2), with Q pre-scaled by QSCALE.
// ---------------------------------------------------------------------------
template <bool A_F32, bool OUT_F32>
__global__ __launch_bounds__(256) void gemm_kernel(
    const void* __restrict__ A0, const void* __restrict__ A1, const void* __restrict__ A2,
    const unsigned short* __restrict__ wt_base, int wt_stride,
    const float* __restrict__ b0, const float* __restrict__ b1, const float* __restrict__ b2,
    void* __restrict__ out_base, size_t out_stride_bytes) {
    __shared__ unsigned short As[128][40];
    __shared__ unsigned short Bs[128][40];
    const int t = threadIdx.x;
    const int lane = t & 63, w = t >> 6;
    const int wr = w >> 1, wc = w & 1;
    const int lr = lane & 15, lg = lane >> 4;
    const int bid = blockIdx.x;
    const int u = (bid & 7) * (gridDim.x >> 3) + (bid >> 3);
    const int xt = u & 3, yt = (u >> 2) & 63, z = u >> 8;
    const void* Ap = z == 0 ? A0 : z == 1 ? A1 : A2;
    const float* bias = z == 0 ? b0 : z == 1 ? b1 : b2;
    const unsigned short* Wt = wt_base + (size_t)z * wt_stride;
    void* outp = (void*)((char*)out_base + (size_t)z * out_stride_bytes);
    const int m0 = yt * 128, n0 = xt * 128;

    f32x4 acc[4][4];
    #pragma unroll
    for (int i = 0; i < 4; ++i)
        #pragma unroll
        for (int j = 0; j < 4; ++j) acc[i][j] = (f32x4){0.f, 0.f, 0.f, 0.f};

    for (int kt = 0; kt < 16; ++kt) {
        const int k0 = kt * 32;
        __syncthreads();
        if (A_F32) {
            const float* A = (const float*)Ap;
            const int mrow = t >> 3, k4 = (t & 7) * 4;
            #pragma unroll
            for (int r = 0; r < 4; ++r) {
                const int m = mrow + 32 * r;
                float4 v = *(const float4*)(A + (size_t)(m0 + m) * ND + k0 + k4);
                unsigned p0, p1;
                CVTPK(p0, v.x, v.y);
                CVTPK(p1, v.z, v.w);
                uint2 pv; pv.x = p0; pv.y = p1;
                *(uint2*)(&As[m][k4]) = pv;
            }
        } else {
            const unsigned short* A = (const unsigned short*)Ap;
            #pragma unroll
            for (int r = 0; r < 2; ++r) {
                const int idx = t + 256 * r;
                const int m = idx >> 2, k8 = (idx & 3) * 8;
                *(bf16x8*)(&As[m][k8]) =
                    *(const bf16x8*)(A + (size_t)(m0 + m) * ND + k0 + k8);
            }
        }
        #pragma unroll
        for (int r = 0; r < 2; ++r) {
            const int idx = t + 256 * r;
            const int n = idx >> 2, k8 = (idx & 3) * 8;
            *(bf16x8*)(&Bs[n][k8]) =
                *(const bf16x8*)(Wt + (size_t)(n0 + n) * ND + k0 + k8);
        }
        __syncthreads();
        bf16x8 af[4], bfv[4];
        #pragma unroll
        for (int mi = 0; mi < 4; ++mi)
            af[mi] = *(const bf16x8*)(&As[wr * 64 + mi * 16 + lr][lg * 8]);
        #pragma unroll
        for (int nj = 0; nj < 4; ++nj)
            bfv[nj] = *(const bf16x8*)(&Bs[wc * 64 + nj * 16 + lr][lg * 8]);
        #pragma unroll
        for (int mi = 0; mi < 4; ++mi)
            #pragma unroll
            for (int nj = 0; nj < 4; ++nj)
                acc[mi][nj] = __builtin_amdgcn_mfma_f32_16x16x32_bf16(
                    af[mi], bfv[nj], acc[mi][nj], 0, 0, 0);
    }

    const float osc = (!OUT_F32 && z == 0) ? QSCALE : 1.0f;
    #pragma unroll
    for (int mi = 0; mi < 4; ++mi) {
        #pragma unroll
        for (int nj = 0; nj < 4; ++nj) {
            const int n = n0 + wc * 64 + nj * 16 + lr;
            const float bv = bias[n];
            #pragma unroll
            for (int r = 0; r < 4; ++r) {
                const int m = m0 + wr * 64 + mi * 16 + lg * 4 + r;
                const float val = (acc[mi][nj][r] + bv) * osc;
                if (OUT_F32) {
                    ((float*)outp)[(size_t)m * ND + n] = val;
                } else {
                    const int bb = m >> 10, s = m & 1023;    // m = b*S + s
                    const int hh = n >> 6, dk = n & 63;      // n = h*64 + dk
                    const size_t off = z == 0 ? qf_off(s, dk)
                                     : z == 1 ? kf_off(s, dk)
                                              : vf_off(s, dk);
                    ((unsigned short*)outp)[((size_t)(bb * NH + hh) << 16) + off] =
                        bfround(val);
                }
            }
        }
    }
}

// ---------------------------------------------------------------------------
// Kernel 3: flash attention, swapped-operand 32x32 MFMA, in-register softmax.
// All Q/K/V loads are from fragment-major layouts: per chunk, 64 lanes x 16B
// fully coalesced at uniform immediate offsets (the R4 strided loads saturated
// the VMEM address pipe: 32 cache lines per load). K double-buffered across
// iterations; V issued in-phase, consumed after softmax.
// ---------------------------------------------------------------------------
struct AttnState {
    f32x16 acc0, acc1;
    float m_st, l_st;
};

__device__ __forceinline__ void attn_step(const bf16x8 (&kf)[8], const bf16x8 (&vv)[8],
                                          const bf16x8 (&qf)[4], int mval,
                                          float* __restrict__ brow, int lane, int hi,
                                          AttnState& st) {
    // mask bias -> per-wave LDS row (ds_write latency hides under QK MFMAs)
    brow[lane] = mval ? 0.f : NEGBIG;

    f32x16 sc0 = {}, sc1 = {};
    __builtin_amdgcn_s_setprio(1);
    sc0 = __builtin_amdgcn_mfma_f32_32x32x16_bf16(kf[0], qf[0], sc0, 0, 0, 0);
    sc1 = __builtin_amdgcn_mfma_f32_32x32x16_bf16(kf[4], qf[0], sc1, 0, 0, 0);
    sc0 = __builtin_amdgcn_mfma_f32_32x32x16_bf16(kf[1], qf[1], sc0, 0, 0, 0);
    sc1 = __builtin_amdgcn_mfma_f32_32x32x16_bf16(kf[5], qf[1], sc1, 0, 0, 0);
    sc0 = __builtin_amdgcn_mfma_f32_32x32x16_bf16(kf[2], qf[2], sc0, 0, 0, 0);
    sc1 = __builtin_amdgcn_mfma_f32_32x32x16_bf16(kf[6], qf[2], sc1, 0, 0, 0);
    sc0 = __builtin_amdgcn_mfma_f32_32x32x16_bf16(kf[3], qf[3], sc0, 0, 0, 0);
    sc1 = __builtin_amdgcn_mfma_f32_32x32x16_bf16(kf[7], qf[3], sc1, 0, 0, 0);
    __builtin_amdgcn_s_setprio(0);

    // mask bias: rows of reg-group mm are 8*mm + 4*hi + {0..3}
    {
        const float* bl = brow + 4 * hi;
        #pragma unroll
        for (int mm = 0; mm < 4; ++mm) {
            const f32x4 bv0 = *(const f32x4*)(bl + 8 * mm);
            const f32x4 bv1 = *(const f32x4*)(bl + 32 + 8 * mm);
            #pragma unroll
            for (int c = 0; c < 4; ++c) {
                sc0[4 * mm + c] += bv0[c];
                sc1[4 * mm + c] += bv1[c];
            }
        }
    }

    // row max (lane holds 32 of 64 kv entries; partner lane has the rest)
    float tv[16];
    #pragma unroll
    for (int r = 0; r < 16; ++r) tv[r] = fmaxf(sc0[r], sc1[r]);
    #pragma unroll
    for (int s = 8; s > 0; s >>= 1)
        #pragma unroll
        for (int r = 0; r < 16; ++r)
            if (r < s) tv[r] = fmaxf(tv[r], tv[r + s]);
    const float mx = fmaxf(tv[0], __shfl_xor(tv[0], 32));
    const float mn = fmaxf(st.m_st, mx);

    // exp2 + row sum
    #pragma unroll
    for (int r = 0; r < 16; ++r) {
        sc0[r] = __builtin_amdgcn_exp2f(sc0[r] - mn);
        sc1[r] = __builtin_amdgcn_exp2f(sc1[r] - mn);
    }
    #pragma unroll
    for (int r = 0; r < 16; ++r) tv[r] = sc0[r] + sc1[r];
    #pragma unroll
    for (int s = 8; s > 0; s >>= 1)
        #pragma unroll
        for (int r = 0; r < 16; ++r)
            if (r < s) tv[r] += tv[r + s];
    const float rs = tv[0] + __shfl_xor(tv[0], 32);

    const bool ch = mn > st.m_st;
    if (__any(ch)) {
        const float f = __builtin_amdgcn_exp2f(st.m_st - mn);
        st.l_st = st.l_st * f + rs;
        st.m_st = mn;
        #pragma unroll
        for (int r = 0; r < 16; ++r) { st.acc0[r] *= f; st.acc1[r] *= f; }
    } else {
        st.l_st += rs;
    }

    // P -> bf16 PV B-frags in-register (T12): words w[m] cover rows
    // 8m+4hi+{0..3}; swap(w[m], w[m+1]) yields frag regs (lo->{0,1}, hi->{2,3})
    union U8 { unsigned u[4]; bf16x8 v; };
    bf16x8 pA0, pA1, pB0, pB1;
    {
        unsigned w00, w01, w10, w11, w20, w21, w30, w31;
        CVTPK(w00, sc0[0], sc0[1]);  CVTPK(w01, sc0[2], sc0[3]);
        CVTPK(w10, sc0[4], sc0[5]);  CVTPK(w11, sc0[6], sc0[7]);
        CVTPK(w20, sc0[8], sc0[9]);  CVTPK(w21, sc0[10], sc0[11]);
        CVTPK(w30, sc0[12], sc0[13]); CVTPK(w31, sc0[14], sc0[15]);
        PLSWAP(w00, w10); PLSWAP(w01, w11);
        PLSWAP(w20, w30); PLSWAP(w21, w31);
        U8 f0; f0.u[0] = w00; f0.u[1] = w01; f0.u[2] = w10; f0.u[3] = w11;
        U8 f1; f1.u[0] = w20; f1.u[1] = w21; f1.u[2] = w30; f1.u[3] = w31;
        pA0 = f0.v; pA1 = f1.v;
    }
    {
        unsigned w00, w01, w10, w11, w20, w21, w30, w31;
        CVTPK(w00, sc1[0], sc1[1]);  CVTPK(w01, sc1[2], sc1[3]);
        CVTPK(w10, sc1[4], sc1[5]);  CVTPK(w11, sc1[6], sc1[7]);
        CVTPK(w20, sc1[8], sc1[9]);  CVTPK(w21, sc1[10], sc1[11]);
        CVTPK(w30, sc1[12], sc1[13]); CVTPK(w31, sc1[14], sc1[15]);
        PLSWAP(w00, w10); PLSWAP(w01, w11);
        PLSWAP(w20, w30); PLSWAP(w21, w31);
        U8 f0; f0.u[0] = w00; f0.u[1] = w01; f0.u[2] = w10; f0.u[3] = w11;
        U8 f1; f1.u[0] = w20; f1.u[1] = w21; f1.u[2] = w30; f1.u[3] = w31;
        pB0 = f0.v; pB1 = f1.v;
    }

    // O^T += V^T P
    __builtin_amdgcn_s_setprio(1);
    st.acc0 = __builtin_amdgcn_mfma_f32_32x32x16_bf16(vv[0], pA0, st.acc0, 0, 0, 0);
    st.acc1 = __builtin_amdgcn_mfma_f32_32x32x16_bf16(vv[4], pA0, st.acc1, 0, 0, 0);
    st.acc0 = __builtin_amdgcn_mfma_f32_32x32x16_bf16(vv[1], pA1, st.acc0, 0, 0, 0);
    st.acc1 = __builtin_amdgcn_mfma_f32_32x32x16_bf16(vv[5], pA1, st.acc1, 0, 0, 0);
    st.acc0 = __builtin_amdgcn_mfma_f32_32x32x16_bf16(vv[2], pB0, st.acc0, 0, 0, 0);
    st.acc1 = __builtin_amdgcn_mfma_f32_32x32x16_bf16(vv[6], pB0, st.acc1, 0, 0, 0);
    st.acc0 = __builtin_amdgcn_mfma_f32_32x32x16_bf16(vv[3], pB1, st.acc0, 0, 0, 0);
    st.acc1 = __builtin_amdgcn_mfma_f32_32x32x16_bf16(vv[7], pB1, st.acc1, 0, 0, 0);
    __builtin_amdgcn_s_setprio(0);
}

__global__ __launch_bounds__(256, 2) void attn_kernel(const unsigned short* __restrict__ QF,
                                                      const unsigned short* __restrict__ KF,
                                                      const unsigned short* __restrict__ VF,
                                                      const int* __restrict__ mask,
                                                      unsigned short* __restrict__ Xb) {
    __shared__ float bias_lds[4][64];
    const int t = threadIdx.x;
    const int lane = t & 63, w = t >> 6;
    const int q32 = lane & 31, hi = lane >> 5;
    // XCD swizzle: 8 q-tiles of one head contiguous on one XCD
    const int bid = blockIdx.x;                  // 512 blocks
    const int u = (bid & 7) * 64 + (bid >> 3);
    const int bh = u >> 3, xq = u & 7;
    const int b = bh >> 3, h = bh & 7;
    const int q = xq * 128 + w * 32 + q32;
    const unsigned short* QFh = QF + ((size_t)bh << 16);
    const unsigned short* KFh = KF + ((size_t)bh << 16);
    const unsigned short* VFh = VF + ((size_t)bh << 16);
    const int* mk = mask + b * NS;
    float* brow = &bias_lds[w][0];

    // Q fragments: 4 coalesced chunk loads (qt = xq*4 + w)
    bf16x8 qf[4];
    {
        const unsigned short* Qp = QFh + (size_t)(xq * 16 + w * 4) * 512 + lane * 8;
        qf[0] = *(const bf16x8*)(Qp + 0 * 512);
        qf[1] = *(const bf16x8*)(Qp + 1 * 512);
        qf[2] = *(const bf16x8*)(Qp + 2 * 512);
        qf[3] = *(const bf16x8*)(Qp + 3 * 512);
    }

    AttnState st;
    st.acc0 = (f32x16){}; st.acc1 = (f32x16){};
    st.m_st = -1.0e30f; st.l_st = 0.f;

    bf16x8 kA[8], kB[8], vv[8];

#define LOADK(dst, itx) do {                                                   \
        const unsigned short* _p = KFh + (size_t)(itx) * 4096 + lane * 8;      \
        dst[0] = *(const bf16x8*)(_p + 0 * 512);                               \
        dst[1] = *(const bf16x8*)(_p + 1 * 512);                               \
        dst[2] = *(const bf16x8*)(_p + 2 * 512);                               \
        dst[3] = *(const bf16x8*)(_p + 3 * 512);                               \
        dst[4] = *(const bf16x8*)(_p + 4 * 512);                               \
        dst[5] = *(const bf16x8*)(_p + 5 * 512);                               \
        dst[6] = *(const bf16x8*)(_p + 6 * 512);                               \
        dst[7] = *(const bf16x8*)(_p + 7 * 512);                               \
    } while (0)

#define LOADV(dst, itx) do {                                                   \
        const unsigned short* _p = VFh + (size_t)(itx) * 4096 + lane * 8;      \
        dst[0] = *(const bf16x8*)(_p + 0 * 512);                               \
        dst[1] = *(const bf16x8*)(_p + 1 * 512);                               \
        dst[2] = *(const bf16x8*)(_p + 2 * 512);                               \
        dst[3] = *(const bf16x8*)(_p + 3 * 512);                               \
        dst[4] = *(const bf16x8*)(_p + 4 * 512);                               \
        dst[5] = *(const bf16x8*)(_p + 5 * 512);                               \
        dst[6] = *(const bf16x8*)(_p + 6 * 512);                               \
        dst[7] = *(const bf16x8*)(_p + 7 * 512);                               \
    } while (0)

    LOADK(kA, 0);
    #pragma unroll 1
    for (int ii = 0; ii < 8; ++ii) {
        const int itE = ii * 2, itO = itE + 1;
        // even phase: V(itE) + K(itO) in flight; compute on kA
        const int mE = mk[itE * 64 + lane];
        LOADV(vv, itE);
        LOADK(kB, itO);
        __builtin_amdgcn_sched_barrier(0);
        attn_step(kA, vv, qf, mE, brow, lane, hi, st);
        // odd phase: V(itO) + K(itE+2) in flight; compute on kB
        const int mO = mk[itO * 64 + lane];
        const int itN = itO + 1 > 15 ? 15 : itO + 1;
        LOADV(vv, itO);
        LOADK(kA, itN);
        __builtin_amdgcn_sched_barrier(0);
        attn_step(kB, vv, qf, mO, brow, lane, hi, st);
    }
#undef LOADK
#undef LOADV

    // epilogue: X[b][q][h*64+dk] = O^T / l ; dk = od*32 + 8*mm + 4*hi + c
    const float inv = st.l_st > 0.f ? 1.f / st.l_st : 0.f;
    unsigned short* Xp = Xb + (size_t)(b * NS + q) * ND + h * 64 + 4 * hi;
    #pragma unroll
    for (int mm = 0; mm < 4; ++mm) {
        unsigned w0, w1;
        CVTPK(w0, st.acc0[4 * mm] * inv, st.acc0[4 * mm + 1] * inv);
        CVTPK(w1, st.acc0[4 * mm + 2] * inv, st.acc0[4 * mm + 3] * inv);
        uint2 pv; pv.x = w0; pv.y = w1;
        *(uint2*)(Xp + 8 * mm) = pv;
        CVTPK(w0, st.acc1[4 * mm] * inv, st.acc1[4 * mm + 1] * inv);
        CVTPK(w1, st.acc1[4 * mm + 2] * inv, st.acc1[4 * mm + 3] * inv);
        pv.x = w0; pv.y = w1;
        *(uint2*)(Xp + 32 + 8 * mm) = pv;
    }
}

// ---------------------------------------------------------------------------
// Host launcher. Workspace (bf16 elements): wt(4*512*512), QF, KF, VF, Xb.
// ---------------------------------------------------------------------------
extern "C" void kernel_launch(void* const* d_in, const int* in_sizes, int n_in,
                              void* d_out, int out_size, void* d_ws, size_t ws_size,
                              hipStream_t stream) {
    const float* query = (const float*)d_in[0];
    const float* key   = (const float*)d_in[1];
    const float* value = (const float*)d_in[2];
    const int*   mask  = (const int*)d_in[3];
    const float* Wq = (const float*)d_in[4];
    const float* bq = (const float*)d_in[5];
    const float* Wk = (const float*)d_in[6];
    const float* bk = (const float*)d_in[7];
    const float* Wv = (const float*)d_in[8];
    const float* bv = (const float*)d_in[9];
    const float* Wo = (const float*)d_in[10];
    const float* bo = (const float*)d_in[11];

    const size_t HEADSZ = (size_t)NB * NH * NS * NDK;  // 4194304
    unsigned short* wt = (unsigned short*)d_ws;
    unsigned short* QFb = wt + (size_t)4 * ND * ND;
    unsigned short* KFb = QFb + HEADSZ;
    unsigned short* VFb = KFb + HEADSZ;
    unsigned short* Xb  = VFb + HEADSZ;

    // 1. weights -> bf16, transposed
    wt_kernel<<<dim3(8, 8, 4), 256, 0, stream>>>(Wq, Wk, Wv, Wo, wt);

    // 2. QKV projections into fragment-major layouts (z = q/k/v)
    gemm_kernel<true, false><<<768, 256, 0, stream>>>(
        query, key, value, wt, ND * ND, bq, bk, bv, (void*)QFb, HEADSZ * 2);

    // 3. attention (512 blocks, 4 waves each, no barriers)
    attn_kernel<<<512, 256, 0, stream>>>(QFb, KFb, VFb, mask, Xb);

    // 4. output projection (fp32 out)
    gemm_kernel<false, true><<<256, 256, 0, stream>>>(
        Xb, Xb, Xb, wt + (size_t)3 * ND * ND, 0, bo, bo, bo, d_out, 0);
}

// Round 6
// 82.560 us; speedup vs baseline: 1.4263x; 1.0300x over previous
//
#include <hip/hip_runtime.h>
#include <hip/hip_bf16.h>

// Shapes (fixed by the reference)
#define NB 8
#define NS 1024
#define ND 512
#define NH 8
#define NDK 64

typedef __attribute__((ext_vector_type(8))) short bf16x8;
typedef __attribute__((ext_vector_type(4))) float f32x4;
typedef __attribute__((ext_vector_type(16))) float f32x16;

// scores are computed in exp2 domain: Q is pre-scaled by 0.125 * log2(e)
#define QSCALE 0.18033688011112042f
#define NEGBIG -3.0e38f

#define CVTPK(dst, a, b) \
    asm("v_cvt_pk_bf16_f32 %0, %1, %2" : "=v"(dst) : "v"(a), "v"(b))
#define PLSWAP(a, b) \
    asm("v_permlane32_swap_b32 %0, %1" : "+v"(a), "+v"(b))
#define GLOAD16(gp, lp)                                                        \
    __builtin_amdgcn_global_load_lds(                                          \
        (const __attribute__((address_space(1))) unsigned*)(gp),               \
        (__attribute__((address_space(3))) unsigned*)(lp), 16, 0, 0)

__device__ __forceinline__ unsigned short bfround(float f) {
    union { float f; unsigned u; } v; v.f = f;
    unsigned u = v.u;
    u += 0x7fffu + ((u >> 16) & 1u);
    return (unsigned short)(u >> 16);
}

// ---------------------------------------------------------------------------
// Fragment-major global layouts for attention operands (16B chunk = 8 shorts;
// a wave's chunk load is 64 lanes x 16B fully coalesced).
// ---------------------------------------------------------------------------
__device__ __forceinline__ size_t qf_off(int s, int dk) {
    return ((size_t)(((s >> 5) * 4 + (dk >> 4)) * 64 + ((dk >> 3) & 1) * 32 + (s & 31)) << 3) + (dk & 7);
}
__device__ __forceinline__ size_t kf_off(int s, int dk) {
    return ((size_t)(((s >> 6) * 8 + ((s >> 5) & 1) * 4 + (dk >> 4)) * 64 + ((dk >> 3) & 1) * 32 + (s & 31)) << 3) + (dk & 7);
}
__device__ __forceinline__ size_t vf_off(int s, int dk) {
    return ((size_t)(((s >> 6) * 8 + (dk >> 5) * 4 + ((s >> 4) & 3)) * 64 + ((s >> 3) & 1) * 32 + (dk & 31)) << 3) + (s & 7);
}

// ---------------------------------------------------------------------------
// Kernel 1: transpose + convert the four 512x512 fp32 weights ([in][out]) into
// bf16 Wt[out][in].
// ---------------------------------------------------------------------------
__global__ __launch_bounds__(256) void wt_kernel(const float* __restrict__ W0,
                                                 const float* __restrict__ W1,
                                                 const float* __restrict__ W2,
                                                 const float* __restrict__ W3,
                                                 unsigned short* __restrict__ wt) {
    __shared__ float sh[64][65];
    const int z = blockIdx.z;
    const float* W = z == 0 ? W0 : z == 1 ? W1 : z == 2 ? W2 : W3;
    unsigned short* out = wt + (size_t)z * ND * ND;
    const int o0 = blockIdx.x * 64, i0 = blockIdx.y * 64;
    const int tx = threadIdx.x & 63;
    const int ty = threadIdx.x >> 6;  // 0..3
    #pragma unroll
    for (int rr = 0; rr < 16; ++rr) {
        const int row = ty * 16 + rr;  // local i
        sh[row][tx] = W[(size_t)(i0 + row) * ND + o0 + tx];
    }
    __syncthreads();
    #pragma unroll
    for (int rr = 0; rr < 16; ++rr) {
        const int row = ty * 16 + rr;  // local o
        out[(size_t)(o0 + row) * ND + i0 + tx] = bfround(sh[tx][row]);
    }
}

// ---------------------------------------------------------------------------
// Kernel 2: QKV projection GEMM (m97 structure).
// Tile 128x128, BK=32, 4 waves (2x2), wave-tile 64x64 (4x4 frags).
// A (fp32) staged raw into LDS via global_load_lds with a 16B-unit XOR swizzle
// (u ^= row&7) applied on the GLOBAL source (LDS dest linear; read applies the
// same involution) -> conflict-free ds_read_b128 pairs; bf16 conversion via
// cvt_pk at fragment-read time. B (bf16 Wt) staged linear (already
// conflict-free for [R][32] bf16). Epilogue scatters to fragment-major QF/KF/VF.
// ---------------------------------------------------------------------------
__global__ __launch_bounds__(256) void gemm_qkv(
    const float* __restrict__ A0, const float* __restrict__ A1, const float* __restrict__ A2,
    const unsigned short* __restrict__ wt,
    const float* __restrict__ b0, const float* __restrict__ b1, const float* __restrict__ b2,
    unsigned short* __restrict__ outb) {
    __shared__ float Asf[128 * 32];           // 16 KB
    __shared__ unsigned short Bs[128 * 32];   // 8 KB
    const int t = threadIdx.x;
    const int lane = t & 63, w = t >> 6;
    const int wr = w >> 1, wc = w & 1;
    const int lr = lane & 15, lg = lane >> 4;
    const int bid = blockIdx.x;               // 768 blocks
    const int u = (bid & 7) * 96 + (bid >> 3);
    const int xt = u & 3, yt = (u >> 2) & 63, z = u >> 8;
    const float* A = z == 0 ? A0 : z == 1 ? A1 : A2;
    const float* bias = z == 0 ? b0 : z == 1 ? b1 : b2;
    const unsigned short* Wt = wt + (size_t)z * ND * ND;
    unsigned short* outp = outb + (size_t)z * NB * NH * NS * NDK;
    const int m0 = yt * 128, n0 = xt * 128;

    // per-lane staging geometry (constant across ksteps)
    const int a_row = w * 32 + (lane >> 3);             // + j*8
    const int a_gc = ((lane & 7) ^ (lane >> 3)) << 2;   // swizzled fp32 col
    const int b_row = w * 32 + (lane >> 2);             // + j*16
    const int b_gc = (lane & 3) * 8;

    f32x4 acc[4][4];
    #pragma unroll
    for (int i = 0; i < 4; ++i)
        #pragma unroll
        for (int j = 0; j < 4; ++j) acc[i][j] = (f32x4){0.f, 0.f, 0.f, 0.f};

    for (int kt = 0; kt < 16; ++kt) {
        const int k0 = kt * 32;
        __syncthreads();
        #pragma unroll
        for (int j = 0; j < 4; ++j)
            GLOAD16(A + (size_t)(m0 + a_row + j * 8) * ND + k0 + a_gc,
                    Asf + (w * 4 + j) * 256);
        #pragma unroll
        for (int j = 0; j < 2; ++j)
            GLOAD16(Wt + (size_t)(n0 + b_row + j * 16) * ND + k0 + b_gc,
                    Bs + (w * 2 + j) * 512);
        __syncthreads();

        bf16x8 af[4], bfr[4];
        #pragma unroll
        for (int mi = 0; mi < 4; ++mi) {
            const int r = wr * 64 + mi * 16 + lr;
            const int u0 = (2 * lg) ^ (lr & 7), u1 = (2 * lg + 1) ^ (lr & 7);
            const f32x4 x0 = *(const f32x4*)(Asf + r * 32 + u0 * 4);
            const f32x4 x1 = *(const f32x4*)(Asf + r * 32 + u1 * 4);
            unsigned p0, p1, p2, p3;
            CVTPK(p0, x0[0], x0[1]); CVTPK(p1, x0[2], x0[3]);
            CVTPK(p2, x1[0], x1[1]); CVTPK(p3, x1[2], x1[3]);
            union { unsigned uu[4]; bf16x8 v; } c;
            c.uu[0] = p0; c.uu[1] = p1; c.uu[2] = p2; c.uu[3] = p3;
            af[mi] = c.v;
        }
        #pragma unroll
        for (int nj = 0; nj < 4; ++nj)
            bfr[nj] = *(const bf16x8*)(Bs + (wc * 64 + nj * 16 + lr) * 32 + lg * 8);
        #pragma unroll
        for (int mi = 0; mi < 4; ++mi)
            #pragma unroll
            for (int nj = 0; nj < 4; ++nj)
                acc[mi][nj] = __builtin_amdgcn_mfma_f32_16x16x32_bf16(
                    af[mi], bfr[nj], acc[mi][nj], 0, 0, 0);
    }

    const float osc = z == 0 ? QSCALE : 1.0f;
    #pragma unroll
    for (int mi = 0; mi < 4; ++mi) {
        #pragma unroll
        for (int nj = 0; nj < 4; ++nj) {
            const int n = n0 + wc * 64 + nj * 16 + lr;
            const float bv = bias[n];
            #pragma unroll
            for (int r = 0; r < 4; ++r) {
                const int m = m0 + wr * 64 + mi * 16 + lg * 4 + r;
                const float val = (acc[mi][nj][r] + bv) * osc;
                const int bb = m >> 10, s = m & 1023;    // m = b*S + s
                const int hh = n >> 6, dk = n & 63;      // n = h*64 + dk
                const size_t off = z == 0 ? qf_off(s, dk)
                                 : z == 1 ? kf_off(s, dk)
                                          : vf_off(s, dk);
                outp[((size_t)(bb * NH + hh) << 16) + off] = bfround(val);
            }
        }
    }
}

// ---------------------------------------------------------------------------
// Kernel 4: output projection GEMM. Tile 128x64 (512 blocks = 2/CU), BK=32,
// 4 waves (2x2), wave-tile 64x32 (4x2 frags). Both operands bf16 via
// global_load_lds, linear LDS (conflict-free for [R][32] bf16). fp32 output.
// ---------------------------------------------------------------------------
__global__ __launch_bounds__(256) void gemm_out(
    const unsigned short* __restrict__ Xb, const unsigned short* __restrict__ Wt,
    const float* __restrict__ bo, float* __restrict__ outp) {
    __shared__ unsigned short As[128 * 32];   // 8 KB
    __shared__ unsigned short Bs[64 * 32];    // 4 KB
    const int t = threadIdx.x;
    const int lane = t & 63, w = t >> 6;
    const int wr = w >> 1, wc = w & 1;
    const int lr = lane & 15, lg = lane >> 4;
    const int bid = blockIdx.x;               // 512 blocks
    const int u = (bid & 7) * 64 + (bid >> 3);
    const int xt = u & 7, yt = u >> 3;
    const int m0 = yt * 128, n0 = xt * 64;

    const int a_row = w * 32 + (lane >> 2);   // + j*16
    const int b_row = w * 16 + (lane >> 2);
    const int gc = (lane & 3) * 8;

    f32x4 acc[4][2];
    #pragma unroll
    for (int i = 0; i < 4; ++i)
        #pragma unroll
        for (int j = 0; j < 2; ++j) acc[i][j] = (f32x4){0.f, 0.f, 0.f, 0.f};

    for (int kt = 0; kt < 16; ++kt) {
        const int k0 = kt * 32;
        __syncthreads();
        #pragma unroll
        for (int j = 0; j < 2; ++j)
            GLOAD16(Xb + (size_t)(m0 + a_row + j * 16) * ND + k0 + gc,
                    As + (w * 2 + j) * 512);
        GLOAD16(Wt + (size_t)(n0 + b_row) * ND + k0 + gc, Bs + w * 512);
        __syncthreads();

        bf16x8 af[4], bfr[2];
        #pragma unroll
        for (int mi = 0; mi < 4; ++mi)
            af[mi] = *(const bf16x8*)(As + (wr * 64 + mi * 16 + lr) * 32 + lg * 8);
        #pragma unroll
        for (int nj = 0; nj < 2; ++nj)
            bfr[nj] = *(const bf16x8*)(Bs + (wc * 32 + nj * 16 + lr) * 32 + lg * 8);
        #pragma unroll
        for (int mi = 0; mi < 4; ++mi)
            #pragma unroll
            for (int nj = 0; nj < 2; ++nj)
                acc[mi][nj] = __builtin_amdgcn_mfma_f32_16x16x32_bf16(
                    af[mi], bfr[nj], acc[mi][nj], 0, 0, 0);
    }

    #pragma unroll
    for (int mi = 0; mi < 4; ++mi) {
        #pragma unroll
        for (int nj = 0; nj < 2; ++nj) {
            const int n = n0 + wc * 32 + nj * 16 + lr;
            const float bv = bo[n];
            #pragma unroll
            for (int r = 0; r < 4; ++r) {
                const int m = m0 + wr * 64 + mi * 16 + lg * 4 + r;
                outp[(size_t)m * ND + n] = acc[mi][nj][r] + bv;
            }
        }
    }
}

// ---------------------------------------------------------------------------
// Kernel 3: flash attention (unchanged from R5 — fragment-major coalesced
// loads, swapped-operand 32x32 MFMA, in-register softmax, K double-buffer).
// ---------------------------------------------------------------------------
struct AttnState {
    f32x16 acc0, acc1;
    float m_st, l_st;
};

__device__ __forceinline__ void attn_step(const bf16x8 (&kf)[8], const bf16x8 (&vv)[8],
                                          const bf16x8 (&qf)[4], int mval,
                                          float* __restrict__ brow, int lane, int hi,
                                          AttnState& st) {
    brow[lane] = mval ? 0.f : NEGBIG;

    f32x16 sc0 = {}, sc1 = {};
    __builtin_amdgcn_s_setprio(1);
    sc0 = __builtin_amdgcn_mfma_f32_32x32x16_bf16(kf[0], qf[0], sc0, 0, 0, 0);
    sc1 = __builtin_amdgcn_mfma_f32_32x32x16_bf16(kf[4], qf[0], sc1, 0, 0, 0);
    sc0 = __builtin_amdgcn_mfma_f32_32x32x16_bf16(kf[1], qf[1], sc0, 0, 0, 0);
    sc1 = __builtin_amdgcn_mfma_f32_32x32x16_bf16(kf[5], qf[1], sc1, 0, 0, 0);
    sc0 = __builtin_amdgcn_mfma_f32_32x32x16_bf16(kf[2], qf[2], sc0, 0, 0, 0);
    sc1 = __builtin_amdgcn_mfma_f32_32x32x16_bf16(kf[6], qf[2], sc1, 0, 0, 0);
    sc0 = __builtin_amdgcn_mfma_f32_32x32x16_bf16(kf[3], qf[3], sc0, 0, 0, 0);
    sc1 = __builtin_amdgcn_mfma_f32_32x32x16_bf16(kf[7], qf[3], sc1, 0, 0, 0);
    __builtin_amdgcn_s_setprio(0);

    {
        const float* bl = brow + 4 * hi;
        #pragma unroll
        for (int mm = 0; mm < 4; ++mm) {
            const f32x4 bv0 = *(const f32x4*)(bl + 8 * mm);
            const f32x4 bv1 = *(const f32x4*)(bl + 32 + 8 * mm);
            #pragma unroll
            for (int c = 0; c < 4; ++c) {
                sc0[4 * mm + c] += bv0[c];
                sc1[4 * mm + c] += bv1[c];
            }
        }
    }

    float tv[16];
    #pragma unroll
    for (int r = 0; r < 16; ++r) tv[r] = fmaxf(sc0[r], sc1[r]);
    #pragma unroll
    for (int s = 8; s > 0; s >>= 1)
        #pragma unroll
        for (int r = 0; r < 16; ++r)
            if (r < s) tv[r] = fmaxf(tv[r], tv[r + s]);
    const float mx = fmaxf(tv[0], __shfl_xor(tv[0], 32));
    const float mn = fmaxf(st.m_st, mx);

    #pragma unroll
    for (int r = 0; r < 16; ++r) {
        sc0[r] = __builtin_amdgcn_exp2f(sc0[r] - mn);
        sc1[r] = __builtin_amdgcn_exp2f(sc1[r] - mn);
    }
    #pragma unroll
    for (int r = 0; r < 16; ++r) tv[r] = sc0[r] + sc1[r];
    #pragma unroll
    for (int s = 8; s > 0; s >>= 1)
        #pragma unroll
        for (int r = 0; r < 16; ++r)
            if (r < s) tv[r] += tv[r + s];
    const float rs = tv[0] + __shfl_xor(tv[0], 32);

    const bool ch = mn > st.m_st;
    if (__any(ch)) {
        const float f = __builtin_amdgcn_exp2f(st.m_st - mn);
        st.l_st = st.l_st * f + rs;
        st.m_st = mn;
        #pragma unroll
        for (int r = 0; r < 16; ++r) { st.acc0[r] *= f; st.acc1[r] *= f; }
    } else {
        st.l_st += rs;
    }

    union U8 { unsigned u[4]; bf16x8 v; };
    bf16x8 pA0, pA1, pB0, pB1;
    {
        unsigned w00, w01, w10, w11, w20, w21, w30, w31;
        CVTPK(w00, sc0[0], sc0[1]);  CVTPK(w01, sc0[2], sc0[3]);
        CVTPK(w10, sc0[4], sc0[5]);  CVTPK(w11, sc0[6], sc0[7]);
        CVTPK(w20, sc0[8], sc0[9]);  CVTPK(w21, sc0[10], sc0[11]);
        CVTPK(w30, sc0[12], sc0[13]); CVTPK(w31, sc0[14], sc0[15]);
        PLSWAP(w00, w10); PLSWAP(w01, w11);
        PLSWAP(w20, w30); PLSWAP(w21, w31);
        U8 f0; f0.u[0] = w00; f0.u[1] = w01; f0.u[2] = w10; f0.u[3] = w11;
        U8 f1; f1.u[0] = w20; f1.u[1] = w21; f1.u[2] = w30; f1.u[3] = w31;
        pA0 = f0.v; pA1 = f1.v;
    }
    {
        unsigned w00, w01, w10, w11, w20, w21, w30, w31;
        CVTPK(w00, sc1[0], sc1[1]);  CVTPK(w01, sc1[2], sc1[3]);
        CVTPK(w10, sc1[4], sc1[5]);  CVTPK(w11, sc1[6], sc1[7]);
        CVTPK(w20, sc1[8], sc1[9]);  CVTPK(w21, sc1[10], sc1[11]);
        CVTPK(w30, sc1[12], sc1[13]); CVTPK(w31, sc1[14], sc1[15]);
        PLSWAP(w00, w10); PLSWAP(w01, w11);
        PLSWAP(w20, w30); PLSWAP(w21, w31);
        U8 f0; f0.u[0] = w00; f0.u[1] = w01; f0.u[2] = w10; f0.u[3] = w11;
        U8 f1; f1.u[0] = w20; f1.u[1] = w21; f1.u[2] = w30; f1.u[3] = w31;
        pB0 = f0.v; pB1 = f1.v;
    }

    __builtin_amdgcn_s_setprio(1);
    st.acc0 = __builtin_amdgcn_mfma_f32_32x32x16_bf16(vv[0], pA0, st.acc0, 0, 0, 0);
    st.acc1 = __builtin_amdgcn_mfma_f32_32x32x16_bf16(vv[4], pA0, st.acc1, 0, 0, 0);
    st.acc0 = __builtin_amdgcn_mfma_f32_32x32x16_bf16(vv[1], pA1, st.acc0, 0, 0, 0);
    st.acc1 = __builtin_amdgcn_mfma_f32_32x32x16_bf16(vv[5], pA1, st.acc1, 0, 0, 0);
    st.acc0 = __builtin_amdgcn_mfma_f32_32x32x16_bf16(vv[2], pB0, st.acc0, 0, 0, 0);
    st.acc1 = __builtin_amdgcn_mfma_f32_32x32x16_bf16(vv[6], pB0, st.acc1, 0, 0, 0);
    st.acc0 = __builtin_amdgcn_mfma_f32_32x32x16_bf16(vv[3], pB1, st.acc0, 0, 0, 0);
    st.acc1 = __builtin_amdgcn_mfma_f32_32x32x16_bf16(vv[7], pB1, st.acc1, 0, 0, 0);
    __builtin_amdgcn_s_setprio(0);
}

__global__ __launch_bounds__(256, 2) void attn_kernel(const unsigned short* __restrict__ QF,
                                                      const unsigned short* __restrict__ KF,
                                                      const unsigned short* __restrict__ VF,
                                                      const int* __restrict__ mask,
                                                      unsigned short* __restrict__ Xb) {
    __shared__ float bias_lds[4][64];
    const int t = threadIdx.x;
    const int lane = t & 63, w = t >> 6;
    const int q32 = lane & 31, hi = lane >> 5;
    const int bid = blockIdx.x;                  // 512 blocks
    const int u = (bid & 7) * 64 + (bid >> 3);
    const int bh = u >> 3, xq = u & 7;
    const int b = bh >> 3, h = bh & 7;
    const int q = xq * 128 + w * 32 + q32;
    const unsigned short* QFh = QF + ((size_t)bh << 16);
    const unsigned short* KFh = KF + ((size_t)bh << 16);
    const unsigned short* VFh = VF + ((size_t)bh << 16);
    const int* mk = mask + b * NS;
    float* brow = &bias_lds[w][0];

    bf16x8 qf[4];
    {
        const unsigned short* Qp = QFh + (size_t)(xq * 16 + w * 4) * 512 + lane * 8;
        qf[0] = *(const bf16x8*)(Qp + 0 * 512);
        qf[1] = *(const bf16x8*)(Qp + 1 * 512);
        qf[2] = *(const bf16x8*)(Qp + 2 * 512);
        qf[3] = *(const bf16x8*)(Qp + 3 * 512);
    }

    AttnState st;
    st.acc0 = (f32x16){}; st.acc1 = (f32x16){};
    st.m_st = -1.0e30f; st.l_st = 0.f;

    bf16x8 kA[8], kB[8], vv[8];

#define LOADK(dst, itx) do {                                                   \
        const unsigned short* _p = KFh + (size_t)(itx) * 4096 + lane * 8;      \
        dst[0] = *(const bf16x8*)(_p + 0 * 512);                               \
        dst[1] = *(const bf16x8*)(_p + 1 * 512);                               \
        dst[2] = *(const bf16x8*)(_p + 2 * 512);                               \
        dst[3] = *(const bf16x8*)(_p + 3 * 512);                               \
        dst[4] = *(const bf16x8*)(_p + 4 * 512);                               \
        dst[5] = *(const bf16x8*)(_p + 5 * 512);                               \
        dst[6] = *(const bf16x8*)(_p + 6 * 512);                               \
        dst[7] = *(const bf16x8*)(_p + 7 * 512);                               \
    } while (0)

#define LOADV(dst, itx) do {                                                   \
        const unsigned short* _p = VFh + (size_t)(itx) * 4096 + lane * 8;      \
        dst[0] = *(const bf16x8*)(_p + 0 * 512);                               \
        dst[1] = *(const bf16x8*)(_p + 1 * 512);                               \
        dst[2] = *(const bf16x8*)(_p + 2 * 512);                               \
        dst[3] = *(const bf16x8*)(_p + 3 * 512);                               \
        dst[4] = *(const bf16x8*)(_p + 4 * 512);                               \
        dst[5] = *(const bf16x8*)(_p + 5 * 512);                               \
        dst[6] = *(const bf16x8*)(_p + 6 * 512);                               \
        dst[7] = *(const bf16x8*)(_p + 7 * 512);                               \
    } while (0)

    LOADK(kA, 0);
    #pragma unroll 1
    for (int ii = 0; ii < 8; ++ii) {
        const int itE = ii * 2, itO = itE + 1;
        const int mE = mk[itE * 64 + lane];
        LOADV(vv, itE);
        LOADK(kB, itO);
        __builtin_amdgcn_sched_barrier(0);
        attn_step(kA, vv, qf, mE, brow, lane, hi, st);
        const int mO = mk[itO * 64 + lane];
        const int itN = itO + 1 > 15 ? 15 : itO + 1;
        LOADV(vv, itO);
        LOADK(kA, itN);
        __builtin_amdgcn_sched_barrier(0);
        attn_step(kB, vv, qf, mO, brow, lane, hi, st);
    }
#undef LOADK
#undef LOADV

    const float inv = st.l_st > 0.f ? 1.f / st.l_st : 0.f;
    unsigned short* Xp = Xb + (size_t)(b * NS + q) * ND + h * 64 + 4 * hi;
    #pragma unroll
    for (int mm = 0; mm < 4; ++mm) {
        unsigned w0, w1;
        CVTPK(w0, st.acc0[4 * mm] * inv, st.acc0[4 * mm + 1] * inv);
        CVTPK(w1, st.acc0[4 * mm + 2] * inv, st.acc0[4 * mm + 3] * inv);
        uint2 pv; pv.x = w0; pv.y = w1;
        *(uint2*)(Xp + 8 * mm) = pv;
        CVTPK(w0, st.acc1[4 * mm] * inv, st.acc1[4 * mm + 1] * inv);
        CVTPK(w1, st.acc1[4 * mm + 2] * inv, st.acc1[4 * mm + 3] * inv);
        pv.x = w0; pv.y = w1;
        *(uint2*)(Xp + 32 + 8 * mm) = pv;
    }
}

// ---------------------------------------------------------------------------
// Host launcher. Workspace (bf16 elements): wt(4*512*512), QF, KF, VF, Xb.
// ---------------------------------------------------------------------------
extern "C" void kernel_launch(void* const* d_in, const int* in_sizes, int n_in,
                              void* d_out, int out_size, void* d_ws, size_t ws_size,
                              hipStream_t stream) {
    const float* query = (const float*)d_in[0];
    const float* key   = (const float*)d_in[1];
    const float* value = (const float*)d_in[2];
    const int*   mask  = (const int*)d_in[3];
    const float* Wq = (const float*)d_in[4];
    const float* bq = (const float*)d_in[5];
    const float* Wk = (const float*)d_in[6];
    const float* bk = (const float*)d_in[7];
    const float* Wv = (const float*)d_in[8];
    const float* bv = (const float*)d_in[9];
    const float* Wo = (const float*)d_in[10];
    const float* bo = (const float*)d_in[11];

    const size_t HEADSZ = (size_t)NB * NH * NS * NDK;  // 4194304
    unsigned short* wt = (unsigned short*)d_ws;
    unsigned short* QFb = wt + (size_t)4 * ND * ND;
    unsigned short* KFb = QFb + HEADSZ;
    unsigned short* VFb = KFb + HEADSZ;
    unsigned short* Xb  = VFb + HEADSZ;

    // 1. weights -> bf16, transposed
    wt_kernel<<<dim3(8, 8, 4), 256, 0, stream>>>(Wq, Wk, Wv, Wo, wt);

    // 2. QKV projections into fragment-major layouts (z = q/k/v)
    gemm_qkv<<<768, 256, 0, stream>>>(query, key, value, wt, bq, bk, bv, QFb);

    // 3. attention (512 blocks, 4 waves each, no barriers)
    attn_kernel<<<512, 256, 0, stream>>>(QFb, KFb, VFb, mask, Xb);

    // 4. output projection (fp32 out)
    gemm_out<<<512, 256, 0, stream>>>(Xb, wt + (size_t)3 * ND * ND, bo, (float*)d_out);
}